// Round 14
// baseline (1186.787 us; speedup 1.0000x reference)
//
#include <hip/hip_runtime.h>
#include <hip/hip_bf16.h>
#include <cstddef>

// Problem constants
#define Bz 128
#define Pz 196
#define Fz 2048
#define Ez 512
#define Hz 512
#define Vz 10000
#define Tz 32
#define TM 31                 // time steps
#define Mrows (Bz * TM)       // 3968
#define MPAD 4096
#define G4 (4 * Hz)           // 2048 gate width
#define NPAD 10240            // zero-padded vocab rows for fcWb

typedef __attribute__((ext_vector_type(8))) short bf16x8;
typedef __attribute__((ext_vector_type(4))) float f32x4;

__device__ __forceinline__ void gload_lds16(const void* g, void* l) {
    __builtin_amdgcn_global_load_lds(
        (const __attribute__((address_space(1))) unsigned int*)g,
        (__attribute__((address_space(3))) unsigned int*)l, 16, 0, 0);
}
__device__ __forceinline__ ushort f2b(float x) {
    __hip_bfloat16 b = __float2bfloat16(x);
    return *reinterpret_cast<ushort*>(&b);
}
__device__ __forceinline__ float b2f(ushort u) {
    __hip_bfloat16 b = *reinterpret_cast<__hip_bfloat16*>(&u);
    return __bfloat162float(b);
}

// ---------------------------------------------------------------------------
__global__ __launch_bounds__(256) void meanpool(const float* __restrict__ feat,
                                                float* __restrict__ mean) {
    int idx = blockIdx.x * 256 + threadIdx.x;
    int b = idx >> 9;
    int q = idx & 511;
    const float4* base = reinterpret_cast<const float4*>(feat) +
                         (size_t)b * Pz * (Fz / 4) + q;
    float4 acc = {0.f, 0.f, 0.f, 0.f};
    for (int p = 0; p < Pz; ++p) {
        float4 v = base[(size_t)p * (Fz / 4)];
        acc.x += v.x; acc.y += v.y; acc.z += v.z; acc.w += v.w;
    }
    const float s = 1.0f / (float)Pz;
    acc.x *= s; acc.y *= s; acc.z *= s; acc.w *= s;
    reinterpret_cast<float4*>(mean)[idx] = acc;
}

// ---------------------------------------------------------------------------
__global__ __launch_bounds__(256) void gather_cvt_emb(const float* __restrict__ emb,
                                                      const int* __restrict__ cap,
                                                      ushort* __restrict__ out) {
    int idx = blockIdx.x * 256 + threadIdx.x;        // Mrows * 128
    if (idx >= Mrows * (Ez / 4)) return;
    int m = idx >> 7, kq = idx & 127;
    int b = m / TM;
    int t = m - b * TM;
    int row = cap[b * Tz + t];
    float4 v = reinterpret_cast<const float4*>(emb + (size_t)row * Ez)[kq];
    ushort4 o = {f2b(v.x), f2b(v.y), f2b(v.z), f2b(v.w)};
    reinterpret_cast<ushort4*>(out + (size_t)m * Ez)[kq] = o;
}

// ---------------------------------------------------------------------------
__global__ __launch_bounds__(256) void permute_w(
    const float* __restrict__ Wih, const float* __restrict__ Whh,
    const float* __restrict__ b1,  const float* __restrict__ b2,
    ushort* __restrict__ WihP, ushort* __restrict__ WhhP,
    float* __restrict__ bP) {
    int idx = blockIdx.x * 256 + threadIdx.x;        // 2 * 2048 * 128
    int sel = idx >> 18;
    int rem = idx & ((1 << 18) - 1);
    int o = rem >> 7, kq = rem & 127;
    int j = o >> 2, g = o & 3;
    int in = g * Hz + j;
    if (sel == 0) {
        float4 v = reinterpret_cast<const float4*>(Wih + (size_t)in * Ez)[kq];
        ushort4 u = {f2b(v.x), f2b(v.y), f2b(v.z), f2b(v.w)};
        reinterpret_cast<ushort4*>(WihP + (size_t)o * Ez)[kq] = u;
        if (kq == 0) bP[o] = b1[in] + b2[in];
    } else {
        float4 v = reinterpret_cast<const float4*>(Whh + (size_t)in * Hz)[kq];
        ushort4 u = {f2b(v.x), f2b(v.y), f2b(v.z), f2b(v.w)};
        reinterpret_cast<ushort4*>(WhhP + (size_t)o * Hz)[kq] = u;
    }
}

// ---------------------------------------------------------------------------
__global__ __launch_bounds__(256) void cvt_bf16_pad4(const float* __restrict__ s,
                                                     ushort* __restrict__ d,
                                                     int n4src, int n4dst) {
    int i = blockIdx.x * 256 + threadIdx.x;
    if (i >= n4dst) return;
    ushort4 o;
    if (i < n4src) {
        float4 v = reinterpret_cast<const float4*>(s)[i];
        o.x = f2b(v.x); o.y = f2b(v.y); o.z = f2b(v.z); o.w = f2b(v.w);
    } else {
        o.x = o.y = o.z = o.w = 0;
    }
    reinterpret_cast<ushort4*>(d)[i] = o;
}

// ---------------------------------------------------------------------------
__global__ __launch_bounds__(256) void initk(
    const float* __restrict__ mean,
    const float* __restrict__ Wh, const float* __restrict__ Wc,
    float* __restrict__ partial)
{
    __shared__ float As[64][33];
    __shared__ float Bs2[64][33];
    const int n0 = blockIdx.x * 64;
    const int m0 = blockIdx.y * 64;
    const int kz = blockIdx.z;
    const int tid = threadIdx.x;
    const int tx = tid & 15, ty = tid >> 4;
    float acc[4][4] = {};

    for (int k0 = kz * 256; k0 < kz * 256 + 256; k0 += 32) {
#pragma unroll
        for (int i = 0; i < 2; ++i) {
            int e  = tid + i * 256;
            int r  = e >> 3;
            int cc = (e & 7) << 2;
            float4 va = *reinterpret_cast<const float4*>(
                mean + (size_t)(m0 + r) * Fz + k0 + cc);
            As[r][cc + 0] = va.x; As[r][cc + 1] = va.y;
            As[r][cc + 2] = va.z; As[r][cc + 3] = va.w;
            int n = n0 + r;
            const float* Brow = (n < Hz) ? (Wh + (size_t)n * Fz)
                                         : (Wc + (size_t)(n - Hz) * Fz);
            float4 vb = *reinterpret_cast<const float4*>(Brow + k0 + cc);
            Bs2[r][cc + 0] = vb.x; Bs2[r][cc + 1] = vb.y;
            Bs2[r][cc + 2] = vb.z; Bs2[r][cc + 3] = vb.w;
        }
        __syncthreads();
#pragma unroll
        for (int kk = 0; kk < 32; ++kk) {
            float a[4], bb[4];
#pragma unroll
            for (int i = 0; i < 4; ++i) a[i] = As[ty * 4 + i][kk];
#pragma unroll
            for (int j = 0; j < 4; ++j) bb[j] = Bs2[tx * 4 + j][kk];
#pragma unroll
            for (int i = 0; i < 4; ++i)
#pragma unroll
                for (int j = 0; j < 4; ++j)
                    acc[i][j] += a[i] * bb[j];
        }
        __syncthreads();
    }
#pragma unroll
    for (int i = 0; i < 4; ++i)
#pragma unroll
        for (int j = 0; j < 4; ++j)
            partial[((size_t)kz * 128 + m0 + ty * 4 + i) * 1024 + n0 + tx * 4 + j]
                = acc[i][j];
}

// ---------------------------------------------------------------------------
__global__ __launch_bounds__(256) void init_reduce(
    const float* __restrict__ partial,
    const float* __restrict__ bh, const float* __restrict__ bc,
    ushort* __restrict__ haHi, ushort* __restrict__ haLo,
    float* __restrict__ c0f)
{
    int idx = blockIdx.x * 256 + threadIdx.x;
    if (idx >= 128 * 1024) return;
    int m = idx >> 10, n = idx & 1023;
    float s = 0.f;
#pragma unroll
    for (int z = 0; z < 8; ++z)
        s += partial[((size_t)z * 128 + m) * 1024 + n];
    if (n < Hz) {
        s += bh[n];
        ushort hh = f2b(s);
        haHi[(size_t)m * Hz + n] = hh;
        haLo[(size_t)m * Hz + n] = f2b(s - b2f(hh));
    } else {
        c0f[(size_t)m * Hz + (n - Hz)] = s + bc[n - Hz];
    }
}

// ---------------------------------------------------------------------------
// bf16 MFMA GEMM, 128x128 2-phase dbuf + XCD swizzle (used for xg)
__global__ __launch_bounds__(256) void gemm_mfma(
    const ushort* __restrict__ A,
    const ushort* __restrict__ B,
    const float* __restrict__ bias,
    float* __restrict__ C,
    int Nb, int ldc, int K)
{
    __shared__ short Al[2][128 * 32];
    __shared__ short Bl[2][128 * 32];
    const int tid  = threadIdx.x;
    const int w    = tid >> 6;
    const int lane = tid & 63;

    const int nwg  = gridDim.x * gridDim.y;
    int orig = blockIdx.y * gridDim.x + blockIdx.x;
    int q = nwg >> 3, r = nwg & 7;
    int xcd = orig & 7, local = orig >> 3;
    int wgid = (xcd < r ? xcd * (q + 1) : r * (q + 1) + (xcd - r) * q) + local;
    const int m0 = (wgid / gridDim.x) * 128;
    const int n0 = (wgid % gridDim.x) * 128;
    const int wr = w >> 1, wc = w & 1;

    f32x4 acc[4][4] = {};

    const int srow = w * 32 + (lane >> 2);
    const int scol = (lane & 3) * 16;
    const char* Ag = (const char*)(A + (size_t)(m0 + srow) * K) + scol;
    const char* Bg = (const char*)(B + (size_t)(n0 + srow) * K) + scol;
    const size_t rstep = (size_t)16 * K * 2;
    const int ldsb = (w * 32) * 32;

    const int ko = (lane >> 4) * 8;
    const int fr = lane & 15;
    const int nk = K >> 5;

    gload_lds16(Ag,         Al[0] + ldsb);
    gload_lds16(Ag + rstep, Al[0] + ldsb + 16 * 32);
    gload_lds16(Bg,         Bl[0] + ldsb);
    gload_lds16(Bg + rstep, Bl[0] + ldsb + 16 * 32);
    __syncthreads();

    int cur = 0;
    for (int k = 0; k < nk; ++k) {
        if (k + 1 < nk) {
            const size_t kb = (size_t)(k + 1) * 64;
            gload_lds16(Ag + kb,         Al[cur ^ 1] + ldsb);
            gload_lds16(Ag + kb + rstep, Al[cur ^ 1] + ldsb + 16 * 32);
            gload_lds16(Bg + kb,         Bl[cur ^ 1] + ldsb);
            gload_lds16(Bg + kb + rstep, Bl[cur ^ 1] + ldsb + 16 * 32);
        }
        bf16x8 af[4], bf[4];
#pragma unroll
        for (int i = 0; i < 4; ++i)
            af[i] = *reinterpret_cast<const bf16x8*>(&Al[cur][(wr * 64 + i * 16 + fr) * 32 + ko]);
#pragma unroll
        for (int j = 0; j < 4; ++j)
            bf[j] = *reinterpret_cast<const bf16x8*>(&Bl[cur][(wc * 64 + j * 16 + fr) * 32 + ko]);
#pragma unroll
        for (int i = 0; i < 4; ++i)
#pragma unroll
            for (int j = 0; j < 4; ++j)
                acc[i][j] = __builtin_amdgcn_mfma_f32_16x16x32_bf16(
                    af[i], bf[j], acc[i][j], 0, 0, 0);
        __syncthreads();
        cur ^= 1;
    }

    const int r0 = (lane >> 4) * 4;
#pragma unroll
    for (int i = 0; i < 4; ++i) {
        int row = m0 + wr * 64 + i * 16 + r0;
#pragma unroll
        for (int j = 0; j < 4; ++j) {
            int col = n0 + wc * 64 + j * 16 + fr;
            if (col < Nb) {
                float bb = bias ? bias[col] : 0.f;
#pragma unroll
                for (int rr = 0; rr < 4; ++rr)
                    C[(size_t)(row + rr) * ldc + col] = acc[i][j][rr] + bb;
            }
        }
    }
}

// ---------------------------------------------------------------------------
// Fused LSTM step + lagged fc. Grid 320 x 256 thr:
//   blocks 0..255  : gate slice (cg = b & 63, mq = b >> 6) for step t  [t < TM]
//   blocks 256..319: fc for step t-1: out[:, t-1, cols f*160..+160)    [t >= 1]
// fc reads hsb written by the previous launch (kernel-boundary coherent).
__global__ __launch_bounds__(256) void lstm_fused(
    const float* __restrict__ xg,
    const ushort* __restrict__ Whi,
    const ushort* __restrict__ Ah,  const ushort* __restrict__ Alo,
    ushort* __restrict__ Oh, ushort* __restrict__ Ol,
    float* __restrict__ cst, ushort* __restrict__ hsb,
    const ushort* __restrict__ fcWb, const float* __restrict__ fc_b,
    float* __restrict__ out, int t)
{
    const int beta = blockIdx.x;
    const int tid  = threadIdx.x;
    const int wv   = tid >> 6;
    const int lane = tid & 63;
    const int fr   = lane & 15;
    const int hi4  = lane >> 4;

    if (beta >= 256) {
        // ---------------- fc phase: out[:, t-1, :] ----------------
        if (t < 1) return;
        const int f   = beta - 256;       // 0..63
        const int n0  = f * 160;          // 10 n-frags
        const int tm1 = t - 1;
        const int b0  = wv * 32;          // wave covers batches b0..b0+31

        f32x4 acc[2][10] = {};
        const ushort* A0 = hsb + ((size_t)(b0 + fr) * TM + tm1) * Hz;
        const ushort* A1 = hsb + ((size_t)(b0 + 16 + fr) * TM + tm1) * Hz;
#pragma unroll
        for (int kc = 0; kc < 16; ++kc) {
            const size_t koff = (size_t)kc * 32 + hi4 * 8;
            bf16x8 a0 = *reinterpret_cast<const bf16x8*>(A0 + koff);
            bf16x8 a1 = *reinterpret_cast<const bf16x8*>(A1 + koff);
#pragma unroll
            for (int nf = 0; nf < 10; ++nf) {
                bf16x8 bv = *reinterpret_cast<const bf16x8*>(
                    fcWb + (size_t)(n0 + nf * 16 + fr) * Hz + koff);
                acc[0][nf] = __builtin_amdgcn_mfma_f32_16x16x32_bf16(a0, bv, acc[0][nf], 0, 0, 0);
                acc[1][nf] = __builtin_amdgcn_mfma_f32_16x16x32_bf16(a1, bv, acc[1][nf], 0, 0, 0);
            }
        }
        const int r0 = hi4 * 4;
#pragma unroll
        for (int mi = 0; mi < 2; ++mi) {
#pragma unroll
            for (int nf = 0; nf < 10; ++nf) {
                int col = n0 + nf * 16 + fr;
                if (col >= Vz) continue;
                float bb = fc_b[col];
#pragma unroll
                for (int rr = 0; rr < 4; ++rr) {
                    int b = b0 + mi * 16 + r0 + rr;
                    out[((size_t)b * TM + tm1) * Vz + col] = acc[mi][nf][rr] + bb;
                }
            }
        }
        return;
    }

    // ---------------- gate phase: step t ----------------
    if (t >= TM) return;
    __shared__ float Cl[2][32][33];

    const int cg  = beta & 63;
    const int mq  = beta >> 6;
    const int kh  = wv >> 1;              // K-half
    const int ch  = wv & 1;               // col-half (16 cols)
    const int n0  = cg * 32;              // 32 gate cols
    const int j0  = cg * 8;               // 8 h-indices
    const int m0w = mq * 32;              // m quarter

    // prefetch elementwise operands
    const int lm = tid >> 3;
    const int hq = tid & 7;
    const int em = m0w + lm;
    const int ej = j0 + hq;
    const float4 xv = *reinterpret_cast<const float4*>(
        xg + ((size_t)em * TM + t) * G4 + n0 + hq * 4);
    const float cold = cst[(size_t)em * Hz + ej];

    f32x4 acc[2] = {};
    const size_t kbase = (size_t)kh * 256;
    const ushort* Bp  = Whi + (size_t)(n0 + ch * 16 + fr) * Hz + kbase;
    const ushort* Ap0 = Ah  + (size_t)(m0w + fr) * Hz + kbase;
    const ushort* Ap1 = Ah  + (size_t)(m0w + 16 + fr) * Hz + kbase;
    const ushort* Lp0 = Alo + (size_t)(m0w + fr) * Hz + kbase;
    const ushort* Lp1 = Alo + (size_t)(m0w + 16 + fr) * Hz + kbase;

#pragma unroll
    for (int kc = 0; kc < 8; ++kc) {
        const size_t koff = (size_t)kc * 32 + hi4 * 8;
        bf16x8 bv  = *reinterpret_cast<const bf16x8*>(Bp  + koff);
        bf16x8 ah0 = *reinterpret_cast<const bf16x8*>(Ap0 + koff);
        bf16x8 ah1 = *reinterpret_cast<const bf16x8*>(Ap1 + koff);
        bf16x8 al0 = *reinterpret_cast<const bf16x8*>(Lp0 + koff);
        bf16x8 al1 = *reinterpret_cast<const bf16x8*>(Lp1 + koff);
        acc[0] = __builtin_amdgcn_mfma_f32_16x16x32_bf16(ah0, bv, acc[0], 0, 0, 0);
        acc[1] = __builtin_amdgcn_mfma_f32_16x16x32_bf16(ah1, bv, acc[1], 0, 0, 0);
        acc[0] = __builtin_amdgcn_mfma_f32_16x16x32_bf16(al0, bv, acc[0], 0, 0, 0);
        acc[1] = __builtin_amdgcn_mfma_f32_16x16x32_bf16(al1, bv, acc[1], 0, 0, 0);
    }

#pragma unroll
    for (int i = 0; i < 2; ++i)
#pragma unroll
        for (int r = 0; r < 4; ++r)
            Cl[kh][i * 16 + hi4 * 4 + r][ch * 16 + fr] = acc[i][r];
    __syncthreads();

    {
        const int bc = hq * 4;
        float gi = Cl[0][lm][bc + 0] + Cl[1][lm][bc + 0] + xv.x;
        float gf = Cl[0][lm][bc + 1] + Cl[1][lm][bc + 1] + xv.y;
        float gg = Cl[0][lm][bc + 2] + Cl[1][lm][bc + 2] + xv.z;
        float go = Cl[0][lm][bc + 3] + Cl[1][lm][bc + 3] + xv.w;

        float ig = 1.f / (1.f + expf(-gi));
        float fg = 1.f / (1.f + expf(-gf));
        float gt = tanhf(gg);
        float og = 1.f / (1.f + expf(-go));

        float cn = fg * cold + ig * gt;
        float hv = og * tanhf(cn);
        cst[(size_t)em * Hz + ej] = cn;

        ushort hh = f2b(hv);
        ushort hl = f2b(hv - b2f(hh));
        Oh[(size_t)em * Hz + ej] = hh;
        Ol[(size_t)em * Hz + ej] = hl;
        hsb[((size_t)em * TM + t) * Hz + ej] = hh;
    }
}

// ---------------------------------------------------------------------------
extern "C" void kernel_launch(void* const* d_in, const int* in_sizes, int n_in,
                              void* d_out, int out_size, void* d_ws, size_t ws_size,
                              hipStream_t stream) {
    const float* features = (const float*)d_in[0];
    const int*   captions = (const int*)d_in[1];
    const float* emb_W    = (const float*)d_in[2];
    const float* W_ih     = (const float*)d_in[3];
    const float* W_hh     = (const float*)d_in[4];
    const float* b_ih     = (const float*)d_in[5];
    const float* b_hh     = (const float*)d_in[6];
    const float* Wh       = (const float*)d_in[7];
    const float* bh       = (const float*)d_in[8];
    const float* Wc       = (const float*)d_in[9];
    const float* bc       = (const float*)d_in[10];
    const float* fc_W     = (const float*)d_in[11];
    const float* fc_b     = (const float*)d_in[12];
    float* out = (float*)d_out;

    // workspace carve-up
    float* w    = (float*)d_ws;
    float* mean = w;                            // 262144 f
    float* xg   = mean + Bz * Fz;               // 8,126,464 f (partial overlaid)
    float* partial = xg;                        // [8][128][1024] f, used pre-xg
    float* c0f  = xg + (size_t)Mrows * G4;      // 65536 f
    float* bP   = c0f + Bz * Hz;                // 2048 f
    ushort* embg = (ushort*)(bP + G4);          // 3968*512
    ushort* WihP = embg + (size_t)Mrows * Ez;   // 2048*512
    ushort* Whi  = WihP + (size_t)G4 * Ez;      // 2048*512
    ushort* fcWb = Whi + (size_t)G4 * Hz;       // 10240*512
    ushort* hsb  = fcWb + (size_t)NPAD * Hz;    // 4096*512 region (3968 used)
    ushort* haHi = hsb + (size_t)MPAD * Hz;     // 128*512 each below
    ushort* haLo = haHi + Bz * Hz;
    ushort* hbHi = haLo + Bz * Hz;
    ushort* hbLo = hbHi + Bz * Hz;

    meanpool<<<(Bz * Fz / 4) / 256, 256, 0, stream>>>(features, mean);
    gather_cvt_emb<<<(Mrows * (Ez / 4) + 255) / 256, 256, 0, stream>>>(emb_W, captions, embg);
    permute_w<<<(2 * G4 * (Hz / 4)) / 256, 256, 0, stream>>>(
        W_ih, W_hh, b_ih, b_hh, WihP, Whi, bP);
    cvt_bf16_pad4<<<(NPAD * Hz / 4 + 255) / 256, 256, 0, stream>>>(
        fc_W, fcWb, Vz * Hz / 4, NPAD * Hz / 4);

    // init h0/c0
    initk<<<dim3(16, 2, 8), 256, 0, stream>>>(mean, Wh, Wc, partial);
    init_reduce<<<(128 * 1024) / 256, 256, 0, stream>>>(
        partial, bh, bc, haHi, haLo, c0f);

    // x-side gates
    gemm_mfma<<<dim3(G4 / 128, Mrows / 128), 256, 0, stream>>>(
        embg, WihP, bP, xg, G4, G4, Ez);

    // recurrence + lagged fc: 32 launches (t=31 does only fc for t=30)
    for (int t = 0; t <= TM; ++t) {
        const ushort* ih = (t & 1) ? hbHi : haHi;
        const ushort* il = (t & 1) ? hbLo : haLo;
        ushort* oh = (t & 1) ? haHi : hbHi;
        ushort* ol = (t & 1) ? haLo : hbLo;
        lstm_fused<<<320, 256, 0, stream>>>(
            xg, Whi, ih, il, oh, ol, c0f, hsb, fcWb, fc_b, out, t);
    }
}

// Round 15
// 423.232 us; speedup vs baseline: 2.8041x; 2.8041x over previous
//
#include <hip/hip_runtime.h>
#include <hip/hip_bf16.h>
#include <cstddef>

// Problem constants
#define Bz 128
#define Pz 196
#define Fz 2048
#define Ez 512
#define Hz 512
#define Vz 10000
#define Tz 32
#define TM 31                 // time steps
#define Mrows (Bz * TM)       // 3968
#define MPAD 4096
#define G4 (4 * Hz)           // 2048 gate width
#define NPAD 10240            // zero-padded vocab rows for fcWb

typedef __attribute__((ext_vector_type(8))) short bf16x8;
typedef __attribute__((ext_vector_type(4))) float f32x4;

__device__ __forceinline__ void gload_lds16(const void* g, void* l) {
    __builtin_amdgcn_global_load_lds(
        (const __attribute__((address_space(1))) unsigned int*)g,
        (__attribute__((address_space(3))) unsigned int*)l, 16, 0, 0);
}
__device__ __forceinline__ ushort f2b(float x) {
    __hip_bfloat16 b = __float2bfloat16(x);
    return *reinterpret_cast<ushort*>(&b);
}
__device__ __forceinline__ float b2f(ushort u) {
    __hip_bfloat16 b = *reinterpret_cast<__hip_bfloat16*>(&u);
    return __bfloat162float(b);
}

// ---------------------------------------------------------------------------
__global__ __launch_bounds__(256) void meanpool(const float* __restrict__ feat,
                                                float* __restrict__ mean) {
    int idx = blockIdx.x * 256 + threadIdx.x;
    int b = idx >> 9;
    int q = idx & 511;
    const float4* base = reinterpret_cast<const float4*>(feat) +
                         (size_t)b * Pz * (Fz / 4) + q;
    float4 acc = {0.f, 0.f, 0.f, 0.f};
    for (int p = 0; p < Pz; ++p) {
        float4 v = base[(size_t)p * (Fz / 4)];
        acc.x += v.x; acc.y += v.y; acc.z += v.z; acc.w += v.w;
    }
    const float s = 1.0f / (float)Pz;
    acc.x *= s; acc.y *= s; acc.z *= s; acc.w *= s;
    reinterpret_cast<float4*>(mean)[idx] = acc;
}

// ---------------------------------------------------------------------------
// merged prep: emb gather+cvt | W_ih/W_hh permute+cvt | fc_W cvt+pad
// index space: [0, Mrows*128) | [.., +2*2048*128) | [.., +NPAD*128)
#define PR0 (Mrows * 128)                 // 507,904
#define PR1 (PR0 + 2 * G4 * 128)          // +524,288
#define PR2 (PR1 + NPAD * 128)            // +1,310,720  total 2,342,912
__global__ __launch_bounds__(256) void prep_all(
    const float* __restrict__ emb,  const int* __restrict__ cap,
    const float* __restrict__ Wih,  const float* __restrict__ Whh,
    const float* __restrict__ b1,   const float* __restrict__ b2,
    const float* __restrict__ fcW,
    ushort* __restrict__ embg, ushort* __restrict__ WihP,
    ushort* __restrict__ WhhP, float* __restrict__ bP,
    ushort* __restrict__ fcWb)
{
    int idx = blockIdx.x * 256 + threadIdx.x;
    if (idx < PR0) {
        // gather caption embeddings + cvt bf16
        int m = idx >> 7, kq = idx & 127;
        int b = m / TM;
        int t = m - b * TM;
        int row = cap[b * Tz + t];
        float4 v = reinterpret_cast<const float4*>(emb + (size_t)row * Ez)[kq];
        ushort4 o = {f2b(v.x), f2b(v.y), f2b(v.z), f2b(v.w)};
        reinterpret_cast<ushort4*>(embg + (size_t)m * Ez)[kq] = o;
    } else if (idx < PR1) {
        // permute W rows g*512+j -> 4j+g, cvt bf16; bP = b_ih + b_hh
        int rem = idx - PR0;
        int sel = rem >> 18;
        rem &= (1 << 18) - 1;
        int o = rem >> 7, kq = rem & 127;
        int j = o >> 2, g = o & 3;
        int in = g * Hz + j;
        if (sel == 0) {
            float4 v = reinterpret_cast<const float4*>(Wih + (size_t)in * Ez)[kq];
            ushort4 u = {f2b(v.x), f2b(v.y), f2b(v.z), f2b(v.w)};
            reinterpret_cast<ushort4*>(WihP + (size_t)o * Ez)[kq] = u;
            if (kq == 0) bP[o] = b1[in] + b2[in];
        } else {
            float4 v = reinterpret_cast<const float4*>(Whh + (size_t)in * Hz)[kq];
            ushort4 u = {f2b(v.x), f2b(v.y), f2b(v.z), f2b(v.w)};
            reinterpret_cast<ushort4*>(WhhP + (size_t)o * Hz)[kq] = u;
        }
    } else if (idx < PR2) {
        // fc_W -> bf16, zero-padded to NPAD rows
        int i = idx - PR1;                 // float4 group index
        ushort4 o;
        if (i < Vz * Hz / 4) {
            float4 v = reinterpret_cast<const float4*>(fcW)[i];
            o.x = f2b(v.x); o.y = f2b(v.y); o.z = f2b(v.z); o.w = f2b(v.w);
        } else {
            o.x = o.y = o.z = o.w = 0;
        }
        reinterpret_cast<ushort4*>(fcWb)[i] = o;
    }
}

// ---------------------------------------------------------------------------
__global__ __launch_bounds__(256) void initk(
    const float* __restrict__ mean,
    const float* __restrict__ Wh, const float* __restrict__ Wc,
    float* __restrict__ partial)
{
    __shared__ float As[64][33];
    __shared__ float Bs2[64][33];
    const int n0 = blockIdx.x * 64;
    const int m0 = blockIdx.y * 64;
    const int kz = blockIdx.z;
    const int tid = threadIdx.x;
    const int tx = tid & 15, ty = tid >> 4;
    float acc[4][4] = {};

    for (int k0 = kz * 256; k0 < kz * 256 + 256; k0 += 32) {
#pragma unroll
        for (int i = 0; i < 2; ++i) {
            int e  = tid + i * 256;
            int r  = e >> 3;
            int cc = (e & 7) << 2;
            float4 va = *reinterpret_cast<const float4*>(
                mean + (size_t)(m0 + r) * Fz + k0 + cc);
            As[r][cc + 0] = va.x; As[r][cc + 1] = va.y;
            As[r][cc + 2] = va.z; As[r][cc + 3] = va.w;
            int n = n0 + r;
            const float* Brow = (n < Hz) ? (Wh + (size_t)n * Fz)
                                         : (Wc + (size_t)(n - Hz) * Fz);
            float4 vb = *reinterpret_cast<const float4*>(Brow + k0 + cc);
            Bs2[r][cc + 0] = vb.x; Bs2[r][cc + 1] = vb.y;
            Bs2[r][cc + 2] = vb.z; Bs2[r][cc + 3] = vb.w;
        }
        __syncthreads();
#pragma unroll
        for (int kk = 0; kk < 32; ++kk) {
            float a[4], bb[4];
#pragma unroll
            for (int i = 0; i < 4; ++i) a[i] = As[ty * 4 + i][kk];
#pragma unroll
            for (int j = 0; j < 4; ++j) bb[j] = Bs2[tx * 4 + j][kk];
#pragma unroll
            for (int i = 0; i < 4; ++i)
#pragma unroll
                for (int j = 0; j < 4; ++j)
                    acc[i][j] += a[i] * bb[j];
        }
        __syncthreads();
    }
#pragma unroll
    for (int i = 0; i < 4; ++i)
#pragma unroll
        for (int j = 0; j < 4; ++j)
            partial[((size_t)kz * 128 + m0 + ty * 4 + i) * 1024 + n0 + tx * 4 + j]
                = acc[i][j];
}

// ---------------------------------------------------------------------------
__global__ __launch_bounds__(256) void init_reduce(
    const float* __restrict__ partial,
    const float* __restrict__ bh, const float* __restrict__ bc,
    ushort* __restrict__ haHi, ushort* __restrict__ haLo,
    float* __restrict__ c0f)
{
    int idx = blockIdx.x * 256 + threadIdx.x;
    if (idx >= 128 * 1024) return;
    int m = idx >> 10, n = idx & 1023;
    float s = 0.f;
#pragma unroll
    for (int z = 0; z < 8; ++z)
        s += partial[((size_t)z * 128 + m) * 1024 + n];
    if (n < Hz) {
        s += bh[n];
        ushort hh = f2b(s);
        haHi[(size_t)m * Hz + n] = hh;
        haLo[(size_t)m * Hz + n] = f2b(s - b2f(hh));
    } else {
        c0f[(size_t)m * Hz + (n - Hz)] = s + bc[n - Hz];
    }
}

// ---------------------------------------------------------------------------
// bf16 MFMA GEMM, 128x128 2-phase dbuf + XCD swizzle (used for xg)
__global__ __launch_bounds__(256) void gemm_mfma(
    const ushort* __restrict__ A,
    const ushort* __restrict__ B,
    const float* __restrict__ bias,
    float* __restrict__ C,
    int Nb, int ldc, int K)
{
    __shared__ short Al[2][128 * 32];
    __shared__ short Bl[2][128 * 32];
    const int tid  = threadIdx.x;
    const int w    = tid >> 6;
    const int lane = tid & 63;

    const int nwg  = gridDim.x * gridDim.y;
    int orig = blockIdx.y * gridDim.x + blockIdx.x;
    int q = nwg >> 3, r = nwg & 7;
    int xcd = orig & 7, local = orig >> 3;
    int wgid = (xcd < r ? xcd * (q + 1) : r * (q + 1) + (xcd - r) * q) + local;
    const int m0 = (wgid / gridDim.x) * 128;
    const int n0 = (wgid % gridDim.x) * 128;
    const int wr = w >> 1, wc = w & 1;

    f32x4 acc[4][4] = {};

    const int srow = w * 32 + (lane >> 2);
    const int scol = (lane & 3) * 16;
    const char* Ag = (const char*)(A + (size_t)(m0 + srow) * K) + scol;
    const char* Bg = (const char*)(B + (size_t)(n0 + srow) * K) + scol;
    const size_t rstep = (size_t)16 * K * 2;
    const int ldsb = (w * 32) * 32;

    const int ko = (lane >> 4) * 8;
    const int fr = lane & 15;
    const int nk = K >> 5;

    gload_lds16(Ag,         Al[0] + ldsb);
    gload_lds16(Ag + rstep, Al[0] + ldsb + 16 * 32);
    gload_lds16(Bg,         Bl[0] + ldsb);
    gload_lds16(Bg + rstep, Bl[0] + ldsb + 16 * 32);
    __syncthreads();

    int cur = 0;
    for (int k = 0; k < nk; ++k) {
        if (k + 1 < nk) {
            const size_t kb = (size_t)(k + 1) * 64;
            gload_lds16(Ag + kb,         Al[cur ^ 1] + ldsb);
            gload_lds16(Ag + kb + rstep, Al[cur ^ 1] + ldsb + 16 * 32);
            gload_lds16(Bg + kb,         Bl[cur ^ 1] + ldsb);
            gload_lds16(Bg + kb + rstep, Bl[cur ^ 1] + ldsb + 16 * 32);
        }
        bf16x8 af[4], bf[4];
#pragma unroll
        for (int i = 0; i < 4; ++i)
            af[i] = *reinterpret_cast<const bf16x8*>(&Al[cur][(wr * 64 + i * 16 + fr) * 32 + ko]);
#pragma unroll
        for (int j = 0; j < 4; ++j)
            bf[j] = *reinterpret_cast<const bf16x8*>(&Bl[cur][(wc * 64 + j * 16 + fr) * 32 + ko]);
#pragma unroll
        for (int i = 0; i < 4; ++i)
#pragma unroll
            for (int j = 0; j < 4; ++j)
                acc[i][j] = __builtin_amdgcn_mfma_f32_16x16x32_bf16(
                    af[i], bf[j], acc[i][j], 0, 0, 0);
        __syncthreads();
        cur ^= 1;
    }

    const int r0 = (lane >> 4) * 4;
#pragma unroll
    for (int i = 0; i < 4; ++i) {
        int row = m0 + wr * 64 + i * 16 + r0;
#pragma unroll
        for (int j = 0; j < 4; ++j) {
            int col = n0 + wc * 64 + j * 16 + fr;
            if (col < Nb) {
                float bb = bias ? bias[col] : 0.f;
#pragma unroll
                for (int rr = 0; rr < 4; ++rr)
                    C[(size_t)(row + rr) * ldc + col] = acc[i][j][rr] + bb;
            }
        }
    }
}

// ---------------------------------------------------------------------------
// fc projection: 256x256 tile, BK=32, 4 LDS buffers (128 KB), depth-3
// prefetch with counted vmcnt(12), chunk-swizzled LDS (both-sides), setprio.
__global__ __launch_bounds__(512) void fc8(
    const ushort* __restrict__ A,   // [MPAD][512]
    const ushort* __restrict__ B,   // [NPAD][512]
    const float* __restrict__ bias,
    float* __restrict__ C)          // [3968][10000]
{
    __shared__ short Lds[4][2][256 * 32];   // 4 bufs x {A,B} x 16 KB = 128 KB

    const int tid  = threadIdx.x;
    const int w    = tid >> 6;          // 0..7
    const int lane = tid & 63;
    const int fr   = lane & 15;

    // bijective XCD swizzle (640 = 8 * 80)
    int orig = blockIdx.x;
    int wgid = (orig & 7) * 80 + (orig >> 3);
    const int m0 = (wgid / 40) * 256;
    const int n0 = (wgid % 40) * 256;
    const int wr = w >> 2, wc = w & 3;  // 2M x 4N wave grid

    f32x4 acc[8][4] = {};

    const int sw16 = (((lane & 3) ^ ((lane >> 3) & 3)) << 4);
    const int srowA = lane >> 2;        // 0..15 row-within-instr
    const int rsw = (((lane >> 4) ^ ((fr >> 1) & 3)) << 4);

#define FC_STAGE(T_) do {                                                     \
    const int b_ = (T_) & 3;                                                  \
    const size_t kb_ = (size_t)(T_) * 64;                                     \
    _Pragma("unroll")                                                         \
    for (int q_ = 0; q_ < 2; ++q_) {                                          \
        const int R_ = w * 32 + q_ * 16;                                      \
        gload_lds16((const char*)A + (size_t)(m0 + R_ + srowA) * 1024 + kb_ + sw16, \
                    (char*)&Lds[b_][0][0] + R_ * 64);                         \
        gload_lds16((const char*)B + (size_t)(n0 + R_ + srowA) * 1024 + kb_ + sw16, \
                    (char*)&Lds[b_][1][0] + R_ * 64);                         \
    }                                                                         \
} while (0)

#define FC_ITER(K_, VM_) do {                                                 \
    if ((K_) + 3 <= 15) FC_STAGE((K_) + 3);                                   \
    asm volatile("s_waitcnt vmcnt(" #VM_ ")" ::: "memory");                   \
    __builtin_amdgcn_s_barrier();                                             \
    __builtin_amdgcn_sched_barrier(0);                                        \
    const int b_ = (K_) & 3;                                                  \
    const char* Ab_ = (const char*)&Lds[b_][0][0];                            \
    const char* Bb_ = (const char*)&Lds[b_][1][0];                            \
    bf16x8 bfr_[4];                                                           \
    _Pragma("unroll")                                                         \
    for (int j_ = 0; j_ < 4; ++j_)                                            \
        bfr_[j_] = *reinterpret_cast<const bf16x8*>(                          \
            Bb_ + (wc * 64 + j_ * 16 + fr) * 64 + rsw);                       \
    bf16x8 afr_[8];                                                           \
    _Pragma("unroll")                                                         \
    for (int i_ = 0; i_ < 8; ++i_)                                            \
        afr_[i_] = *reinterpret_cast<const bf16x8*>(                          \
            Ab_ + (wr * 128 + i_ * 16 + fr) * 64 + rsw);                      \
    asm volatile("s_waitcnt lgkmcnt(0)" ::: "memory");                        \
    __builtin_amdgcn_sched_barrier(0);                                        \
    __builtin_amdgcn_s_barrier();                                             \
    __builtin_amdgcn_s_setprio(1);                                            \
    _Pragma("unroll")                                                         \
    for (int i_ = 0; i_ < 8; ++i_)                                            \
        _Pragma("unroll")                                                     \
        for (int j_ = 0; j_ < 4; ++j_)                                        \
            acc[i_][j_] = __builtin_amdgcn_mfma_f32_16x16x32_bf16(            \
                afr_[i_], bfr_[j_], acc[i_][j_], 0, 0, 0);                    \
    __builtin_amdgcn_s_setprio(0);                                            \
} while (0)

    FC_STAGE(0);
    FC_STAGE(1);
    FC_STAGE(2);

#pragma unroll 1
    for (int k = 0; k <= 12; ++k) {
        FC_ITER(k, 12);
    }
    FC_ITER(13, 8);
    FC_ITER(14, 4);
    FC_ITER(15, 0);

#undef FC_STAGE
#undef FC_ITER

    const int r0 = (lane >> 4) * 4;
#pragma unroll
    for (int i = 0; i < 8; ++i) {
        int row = m0 + wr * 128 + i * 16 + r0;
        if (row >= Mrows) continue;     // Mrows % 4 == 0 -> whole quad valid
#pragma unroll
        for (int j = 0; j < 4; ++j) {
            int col = n0 + wc * 64 + j * 16 + fr;
            if (col < Vz) {
                float bb = bias[col];
#pragma unroll
                for (int rr = 0; rr < 4; ++rr)
                    C[(size_t)(row + rr) * Vz + col] = acc[i][j][rr] + bb;
            }
        }
    }
}

// ---------------------------------------------------------------------------
// One LSTM step, K-split over waves. Grid (64, 4) x 256 thr.
__global__ __launch_bounds__(256) void lstm_step3(
    const float* __restrict__ xg,
    const ushort* __restrict__ Whi,
    const ushort* __restrict__ Ah,  const ushort* __restrict__ Alo,
    ushort* __restrict__ Oh, ushort* __restrict__ Ol,
    float* __restrict__ cst, ushort* __restrict__ hsb, int t)
{
    __shared__ float Cl[2][32][33];

    const int tid  = threadIdx.x;
    const int w    = tid >> 6;            // 0..3
    const int kh   = w >> 1;              // K-half
    const int ch   = w & 1;               // col-half (16 cols)
    const int lane = tid & 63;
    const int fr   = lane & 15;
    const int hi4  = lane >> 4;
    const int n0   = blockIdx.x * 32;     // 32 gate cols
    const int j0   = blockIdx.x * 8;      // 8 h-indices
    const int m0w  = blockIdx.y * 32;     // m quarter

    // prefetch elementwise operands
    const int lm = tid >> 3;
    const int hq = tid & 7;
    const int em = m0w + lm;
    const int ej = j0 + hq;
    const float4 xv = *reinterpret_cast<const float4*>(
        xg + ((size_t)em * TM + t) * G4 + n0 + hq * 4);
    const float cold = cst[(size_t)em * Hz + ej];

    f32x4 acc[2] = {};
    const size_t kbase = (size_t)kh * 256;
    const ushort* Bp  = Whi + (size_t)(n0 + ch * 16 + fr) * Hz + kbase;
    const ushort* Ap0 = Ah  + (size_t)(m0w + fr) * Hz + kbase;
    const ushort* Ap1 = Ah  + (size_t)(m0w + 16 + fr) * Hz + kbase;
    const ushort* Lp0 = Alo + (size_t)(m0w + fr) * Hz + kbase;
    const ushort* Lp1 = Alo + (size_t)(m0w + 16 + fr) * Hz + kbase;

#pragma unroll
    for (int kc = 0; kc < 8; ++kc) {
        const size_t koff = (size_t)kc * 32 + hi4 * 8;
        bf16x8 bv  = *reinterpret_cast<const bf16x8*>(Bp  + koff);
        bf16x8 ah0 = *reinterpret_cast<const bf16x8*>(Ap0 + koff);
        bf16x8 ah1 = *reinterpret_cast<const bf16x8*>(Ap1 + koff);
        bf16x8 al0 = *reinterpret_cast<const bf16x8*>(Lp0 + koff);
        bf16x8 al1 = *reinterpret_cast<const bf16x8*>(Lp1 + koff);
        acc[0] = __builtin_amdgcn_mfma_f32_16x16x32_bf16(ah0, bv, acc[0], 0, 0, 0);
        acc[1] = __builtin_amdgcn_mfma_f32_16x16x32_bf16(ah1, bv, acc[1], 0, 0, 0);
        acc[0] = __builtin_amdgcn_mfma_f32_16x16x32_bf16(al0, bv, acc[0], 0, 0, 0);
        acc[1] = __builtin_amdgcn_mfma_f32_16x16x32_bf16(al1, bv, acc[1], 0, 0, 0);
    }

#pragma unroll
    for (int i = 0; i < 2; ++i)
#pragma unroll
        for (int r = 0; r < 4; ++r)
            Cl[kh][i * 16 + hi4 * 4 + r][ch * 16 + fr] = acc[i][r];
    __syncthreads();

    {
        const int bc = hq * 4;
        float gi = Cl[0][lm][bc + 0] + Cl[1][lm][bc + 0] + xv.x;
        float gf = Cl[0][lm][bc + 1] + Cl[1][lm][bc + 1] + xv.y;
        float gg = Cl[0][lm][bc + 2] + Cl[1][lm][bc + 2] + xv.z;
        float go = Cl[0][lm][bc + 3] + Cl[1][lm][bc + 3] + xv.w;

        float ig = 1.f / (1.f + expf(-gi));
        float fg = 1.f / (1.f + expf(-gf));
        float gt = tanhf(gg);
        float og = 1.f / (1.f + expf(-go));

        float cn = fg * cold + ig * gt;
        float hv = og * tanhf(cn);
        cst[(size_t)em * Hz + ej] = cn;

        ushort hh = f2b(hv);
        ushort hl = f2b(hv - b2f(hh));
        Oh[(size_t)em * Hz + ej] = hh;
        Ol[(size_t)em * Hz + ej] = hl;
        hsb[((size_t)em * TM + t) * Hz + ej] = hh;
    }
}

// ---------------------------------------------------------------------------
extern "C" void kernel_launch(void* const* d_in, const int* in_sizes, int n_in,
                              void* d_out, int out_size, void* d_ws, size_t ws_size,
                              hipStream_t stream) {
    const float* features = (const float*)d_in[0];
    const int*   captions = (const int*)d_in[1];
    const float* emb_W    = (const float*)d_in[2];
    const float* W_ih     = (const float*)d_in[3];
    const float* W_hh     = (const float*)d_in[4];
    const float* b_ih     = (const float*)d_in[5];
    const float* b_hh     = (const float*)d_in[6];
    const float* Wh       = (const float*)d_in[7];
    const float* bh       = (const float*)d_in[8];
    const float* Wc       = (const float*)d_in[9];
    const float* bc       = (const float*)d_in[10];
    const float* fc_W     = (const float*)d_in[11];
    const float* fc_b     = (const float*)d_in[12];
    float* out = (float*)d_out;

    // workspace carve-up
    float* w    = (float*)d_ws;
    float* mean = w;                            // 262144 f
    float* xg   = mean + Bz * Fz;               // 8,126,464 f (partial overlaid)
    float* partial = xg;                        // [8][128][1024] f, used pre-xg
    float* c0f  = xg + (size_t)Mrows * G4;      // 65536 f
    float* bP   = c0f + Bz * Hz;                // 2048 f
    ushort* embg = (ushort*)(bP + G4);          // 3968*512
    ushort* WihP = embg + (size_t)Mrows * Ez;   // 2048*512
    ushort* Whi  = WihP + (size_t)G4 * Ez;      // 2048*512
    ushort* fcWb = Whi + (size_t)G4 * Hz;       // 10240*512
    ushort* hsb  = fcWb + (size_t)NPAD * Hz;    // 4096*512 region (3968 used)
    ushort* haHi = hsb + (size_t)MPAD * Hz;     // 128*512 each below
    ushort* haLo = haHi + Bz * Hz;
    ushort* hbHi = haLo + Bz * Hz;
    ushort* hbLo = hbHi + Bz * Hz;

    meanpool<<<(Bz * Fz / 4) / 256, 256, 0, stream>>>(features, mean);
    prep_all<<<(PR2 + 255) / 256, 256, 0, stream>>>(
        emb_W, captions, W_ih, W_hh, b_ih, b_hh, fc_W,
        embg, WihP, Whi, bP, fcWb);

    // init h0/c0
    initk<<<dim3(16, 2, 8), 256, 0, stream>>>(mean, Wh, Wc, partial);
    init_reduce<<<(128 * 1024) / 256, 256, 0, stream>>>(
        partial, bh, bc, haHi, haLo, c0f);

    // x-side gates
    gemm_mfma<<<dim3(G4 / 128, Mrows / 128), 256, 0, stream>>>(
        embg, WihP, bP, xg, G4, G4, Ez);

    // recurrence
    for (int t = 0; t < TM; ++t) {
        const ushort* ih = (t & 1) ? hbHi : haHi;
        const ushort* il = (t & 1) ? hbLo : haLo;
        ushort* oh = (t & 1) ? haHi : hbHi;
        ushort* ol = (t & 1) ? haLo : hbLo;
        lstm_step3<<<dim3(64, 4), 256, 0, stream>>>(
            xg, Whi, ih, il, oh, ol, c0f, hsb, t);
    }

    // output projection: depth-3 pipelined, swizzled fc
    fc8<<<640, 512, 0, stream>>>(hsb, fcWb, fc_b, out);
}

// Round 16
// 417.426 us; speedup vs baseline: 2.8431x; 1.0139x over previous
//
#include <hip/hip_runtime.h>
#include <hip/hip_bf16.h>
#include <cstddef>

// Problem constants
#define Bz 128
#define Pz 196
#define Fz 2048
#define Ez 512
#define Hz 512
#define Vz 10000
#define Tz 32
#define TM 31                 // time steps
#define Mrows (Bz * TM)       // 3968
#define MPAD 4096
#define G4 (4 * Hz)           // 2048 gate width
#define NPAD 10240            // zero-padded vocab rows for fcWb

typedef __attribute__((ext_vector_type(8))) short bf16x8;
typedef __attribute__((ext_vector_type(4))) float f32x4;

__device__ __forceinline__ void gload_lds16(const void* g, void* l) {
    __builtin_amdgcn_global_load_lds(
        (const __attribute__((address_space(1))) unsigned int*)g,
        (__attribute__((address_space(3))) unsigned int*)l, 16, 0, 0);
}
__device__ __forceinline__ ushort f2b(float x) {
    __hip_bfloat16 b = __float2bfloat16(x);
    return *reinterpret_cast<ushort*>(&b);
}
__device__ __forceinline__ float b2f(ushort u) {
    __hip_bfloat16 b = *reinterpret_cast<__hip_bfloat16*>(&u);
    return __bfloat162float(b);
}

// ---------------------------------------------------------------------------
__global__ __launch_bounds__(256) void meanpool(const float* __restrict__ feat,
                                                float* __restrict__ mean) {
    int idx = blockIdx.x * 256 + threadIdx.x;
    int b = idx >> 9;
    int q = idx & 511;
    const float4* base = reinterpret_cast<const float4*>(feat) +
                         (size_t)b * Pz * (Fz / 4) + q;
    float4 acc = {0.f, 0.f, 0.f, 0.f};
    for (int p = 0; p < Pz; ++p) {
        float4 v = base[(size_t)p * (Fz / 4)];
        acc.x += v.x; acc.y += v.y; acc.z += v.z; acc.w += v.w;
    }
    const float s = 1.0f / (float)Pz;
    acc.x *= s; acc.y *= s; acc.z *= s; acc.w *= s;
    reinterpret_cast<float4*>(mean)[idx] = acc;
}

// ---------------------------------------------------------------------------
// merged prep: emb gather+cvt | W_ih/W_hh permute+cvt | fc_W cvt+pad
#define PR0 (Mrows * 128)                 // 507,904
#define PR1 (PR0 + 2 * G4 * 128)          // +524,288
#define PR2 (PR1 + NPAD * 128)            // +1,310,720
__global__ __launch_bounds__(256) void prep_all(
    const float* __restrict__ emb,  const int* __restrict__ cap,
    const float* __restrict__ Wih,  const float* __restrict__ Whh,
    const float* __restrict__ b1,   const float* __restrict__ b2,
    const float* __restrict__ fcW,
    ushort* __restrict__ embg, ushort* __restrict__ WihP,
    ushort* __restrict__ WhhP, float* __restrict__ bP,
    ushort* __restrict__ fcWb)
{
    int idx = blockIdx.x * 256 + threadIdx.x;
    if (idx < PR0) {
        int m = idx >> 7, kq = idx & 127;
        int b = m / TM;
        int t = m - b * TM;
        int row = cap[b * Tz + t];
        float4 v = reinterpret_cast<const float4*>(emb + (size_t)row * Ez)[kq];
        ushort4 o = {f2b(v.x), f2b(v.y), f2b(v.z), f2b(v.w)};
        reinterpret_cast<ushort4*>(embg + (size_t)m * Ez)[kq] = o;
    } else if (idx < PR1) {
        int rem = idx - PR0;
        int sel = rem >> 18;
        rem &= (1 << 18) - 1;
        int o = rem >> 7, kq = rem & 127;
        int j = o >> 2, g = o & 3;
        int in = g * Hz + j;
        if (sel == 0) {
            float4 v = reinterpret_cast<const float4*>(Wih + (size_t)in * Ez)[kq];
            ushort4 u = {f2b(v.x), f2b(v.y), f2b(v.z), f2b(v.w)};
            reinterpret_cast<ushort4*>(WihP + (size_t)o * Ez)[kq] = u;
            if (kq == 0) bP[o] = b1[in] + b2[in];
        } else {
            float4 v = reinterpret_cast<const float4*>(Whh + (size_t)in * Hz)[kq];
            ushort4 u = {f2b(v.x), f2b(v.y), f2b(v.z), f2b(v.w)};
            reinterpret_cast<ushort4*>(WhhP + (size_t)o * Hz)[kq] = u;
        }
    } else if (idx < PR2) {
        int i = idx - PR1;
        ushort4 o;
        if (i < Vz * Hz / 4) {
            float4 v = reinterpret_cast<const float4*>(fcW)[i];
            o.x = f2b(v.x); o.y = f2b(v.y); o.z = f2b(v.z); o.w = f2b(v.w);
        } else {
            o.x = o.y = o.z = o.w = 0;
        }
        reinterpret_cast<ushort4*>(fcWb)[i] = o;
    }
}

// ---------------------------------------------------------------------------
__global__ __launch_bounds__(256) void initk(
    const float* __restrict__ mean,
    const float* __restrict__ Wh, const float* __restrict__ Wc,
    float* __restrict__ partial)
{
    __shared__ float As[64][33];
    __shared__ float Bs2[64][33];
    const int n0 = blockIdx.x * 64;
    const int m0 = blockIdx.y * 64;
    const int kz = blockIdx.z;
    const int tid = threadIdx.x;
    const int tx = tid & 15, ty = tid >> 4;
    float acc[4][4] = {};

    for (int k0 = kz * 256; k0 < kz * 256 + 256; k0 += 32) {
#pragma unroll
        for (int i = 0; i < 2; ++i) {
            int e  = tid + i * 256;
            int r  = e >> 3;
            int cc = (e & 7) << 2;
            float4 va = *reinterpret_cast<const float4*>(
                mean + (size_t)(m0 + r) * Fz + k0 + cc);
            As[r][cc + 0] = va.x; As[r][cc + 1] = va.y;
            As[r][cc + 2] = va.z; As[r][cc + 3] = va.w;
            int n = n0 + r;
            const float* Brow = (n < Hz) ? (Wh + (size_t)n * Fz)
                                         : (Wc + (size_t)(n - Hz) * Fz);
            float4 vb = *reinterpret_cast<const float4*>(Brow + k0 + cc);
            Bs2[r][cc + 0] = vb.x; Bs2[r][cc + 1] = vb.y;
            Bs2[r][cc + 2] = vb.z; Bs2[r][cc + 3] = vb.w;
        }
        __syncthreads();
#pragma unroll
        for (int kk = 0; kk < 32; ++kk) {
            float a[4], bb[4];
#pragma unroll
            for (int i = 0; i < 4; ++i) a[i] = As[ty * 4 + i][kk];
#pragma unroll
            for (int j = 0; j < 4; ++j) bb[j] = Bs2[tx * 4 + j][kk];
#pragma unroll
            for (int i = 0; i < 4; ++i)
#pragma unroll
                for (int j = 0; j < 4; ++j)
                    acc[i][j] += a[i] * bb[j];
        }
        __syncthreads();
    }
#pragma unroll
    for (int i = 0; i < 4; ++i)
#pragma unroll
        for (int j = 0; j < 4; ++j)
            partial[((size_t)kz * 128 + m0 + ty * 4 + i) * 1024 + n0 + tx * 4 + j]
                = acc[i][j];
}

// ---------------------------------------------------------------------------
__global__ __launch_bounds__(256) void init_reduce(
    const float* __restrict__ partial,
    const float* __restrict__ bh, const float* __restrict__ bc,
    ushort* __restrict__ haHi, ushort* __restrict__ haLo,
    float* __restrict__ c0f)
{
    int idx = blockIdx.x * 256 + threadIdx.x;
    if (idx >= 128 * 1024) return;
    int m = idx >> 10, n = idx & 1023;
    float s = 0.f;
#pragma unroll
    for (int z = 0; z < 8; ++z)
        s += partial[((size_t)z * 128 + m) * 1024 + n];
    if (n < Hz) {
        s += bh[n];
        ushort hh = f2b(s);
        haHi[(size_t)m * Hz + n] = hh;
        haLo[(size_t)m * Hz + n] = f2b(s - b2f(hh));
    } else {
        c0f[(size_t)m * Hz + (n - Hz)] = s + bc[n - Hz];
    }
}

// ---------------------------------------------------------------------------
// xg GEMM: 128x128 tile, BK=32, 4 LDS buffers (64 KB), depth-3 prefetch,
// counted vmcnt(12), chunk-swizzled LDS, setprio. 4 waves (2M x 2N).
// M=3968 (31 tiles exact), N=2048 (16 tiles exact) -> no edge guards.
__global__ __launch_bounds__(256) void xg8(
    const ushort* __restrict__ A,   // [3968][512] embg
    const ushort* __restrict__ B,   // [2048][512] WihP
    const float* __restrict__ bias, // bP
    float* __restrict__ C)          // xg [3968][2048]
{
    __shared__ short Lds[4][2][128 * 32];   // 4 bufs x {A,B} x 8 KB = 64 KB

    const int tid  = threadIdx.x;
    const int w    = tid >> 6;          // 0..3
    const int lane = tid & 63;
    const int fr   = lane & 15;

    // bijective XCD swizzle (496 = 8 * 62)
    int orig = blockIdx.x;
    int wgid = (orig & 7) * 62 + (orig >> 3);
    const int m0 = (wgid / 16) * 128;
    const int n0 = (wgid % 16) * 128;
    const int wr = w >> 1, wc = w & 1;  // 2M x 2N wave grid

    f32x4 acc[4][4] = {};

    const int sw16 = (((lane & 3) ^ ((lane >> 3) & 3)) << 4);
    const int srowA = lane >> 2;        // 0..15 row-within-instr
    const int rsw = (((lane >> 4) ^ ((fr >> 1) & 3)) << 4);

#define XG_STAGE(T_) do {                                                     \
    const int b_ = (T_) & 3;                                                  \
    const size_t kb_ = (size_t)(T_) * 64;                                     \
    _Pragma("unroll")                                                         \
    for (int q_ = 0; q_ < 2; ++q_) {                                          \
        const int R_ = w * 32 + q_ * 16;                                      \
        gload_lds16((const char*)A + (size_t)(m0 + R_ + srowA) * 1024 + kb_ + sw16, \
                    (char*)&Lds[b_][0][0] + R_ * 64);                         \
        gload_lds16((const char*)B + (size_t)(n0 + R_ + srowA) * 1024 + kb_ + sw16, \
                    (char*)&Lds[b_][1][0] + R_ * 64);                         \
    }                                                                         \
} while (0)

#define XG_ITER(K_, VM_) do {                                                 \
    if ((K_) + 3 <= 15) XG_STAGE((K_) + 3);                                   \
    asm volatile("s_waitcnt vmcnt(" #VM_ ")" ::: "memory");                   \
    __builtin_amdgcn_s_barrier();                                             \
    __builtin_amdgcn_sched_barrier(0);                                        \
    const int b_ = (K_) & 3;                                                  \
    const char* Ab_ = (const char*)&Lds[b_][0][0];                            \
    const char* Bb_ = (const char*)&Lds[b_][1][0];                            \
    bf16x8 bfr_[4];                                                           \
    _Pragma("unroll")                                                         \
    for (int j_ = 0; j_ < 4; ++j_)                                            \
        bfr_[j_] = *reinterpret_cast<const bf16x8*>(                          \
            Bb_ + (wc * 64 + j_ * 16 + fr) * 64 + rsw);                       \
    bf16x8 afr_[4];                                                           \
    _Pragma("unroll")                                                         \
    for (int i_ = 0; i_ < 4; ++i_)                                            \
        afr_[i_] = *reinterpret_cast<const bf16x8*>(                          \
            Ab_ + (wr * 64 + i_ * 16 + fr) * 64 + rsw);                       \
    asm volatile("s_waitcnt lgkmcnt(0)" ::: "memory");                        \
    __builtin_amdgcn_sched_barrier(0);                                        \
    __builtin_amdgcn_s_barrier();                                             \
    __builtin_amdgcn_s_setprio(1);                                            \
    _Pragma("unroll")                                                         \
    for (int i_ = 0; i_ < 4; ++i_)                                            \
        _Pragma("unroll")                                                     \
        for (int j_ = 0; j_ < 4; ++j_)                                        \
            acc[i_][j_] = __builtin_amdgcn_mfma_f32_16x16x32_bf16(            \
                afr_[i_], bfr_[j_], acc[i_][j_], 0, 0, 0);                    \
    __builtin_amdgcn_s_setprio(0);                                            \
} while (0)

    XG_STAGE(0);
    XG_STAGE(1);
    XG_STAGE(2);

#pragma unroll 1
    for (int k = 0; k <= 12; ++k) {
        XG_ITER(k, 12);
    }
    XG_ITER(13, 8);
    XG_ITER(14, 4);
    XG_ITER(15, 0);

#undef XG_STAGE
#undef XG_ITER

    const int r0 = (lane >> 4) * 4;
#pragma unroll
    for (int i = 0; i < 4; ++i) {
        int row = m0 + wr * 64 + i * 16 + r0;
#pragma unroll
        for (int j = 0; j < 4; ++j) {
            int col = n0 + wc * 64 + j * 16 + fr;
            float bb = bias[col];
#pragma unroll
            for (int rr = 0; rr < 4; ++rr)
                C[(size_t)(row + rr) * G4 + col] = acc[i][j][rr] + bb;
        }
    }
}

// ---------------------------------------------------------------------------
// fc projection: 256x256 tile, BK=32, 4 LDS buffers (128 KB), depth-3
// prefetch with counted vmcnt(12), chunk-swizzled LDS, setprio.
__global__ __launch_bounds__(512) void fc8(
    const ushort* __restrict__ A,   // [MPAD][512]
    const ushort* __restrict__ B,   // [NPAD][512]
    const float* __restrict__ bias,
    float* __restrict__ C)          // [3968][10000]
{
    __shared__ short Lds[4][2][256 * 32];   // 128 KB

    const int tid  = threadIdx.x;
    const int w    = tid >> 6;          // 0..7
    const int lane = tid & 63;
    const int fr   = lane & 15;

    int orig = blockIdx.x;
    int wgid = (orig & 7) * 80 + (orig >> 3);
    const int m0 = (wgid / 40) * 256;
    const int n0 = (wgid % 40) * 256;
    const int wr = w >> 2, wc = w & 3;

    f32x4 acc[8][4] = {};

    const int sw16 = (((lane & 3) ^ ((lane >> 3) & 3)) << 4);
    const int srowA = lane >> 2;
    const int rsw = (((lane >> 4) ^ ((fr >> 1) & 3)) << 4);

#define FC_STAGE(T_) do {                                                     \
    const int b_ = (T_) & 3;                                                  \
    const size_t kb_ = (size_t)(T_) * 64;                                     \
    _Pragma("unroll")                                                         \
    for (int q_ = 0; q_ < 2; ++q_) {                                          \
        const int R_ = w * 32 + q_ * 16;                                      \
        gload_lds16((const char*)A + (size_t)(m0 + R_ + srowA) * 1024 + kb_ + sw16, \
                    (char*)&Lds[b_][0][0] + R_ * 64);                         \
        gload_lds16((const char*)B + (size_t)(n0 + R_ + srowA) * 1024 + kb_ + sw16, \
                    (char*)&Lds[b_][1][0] + R_ * 64);                         \
    }                                                                         \
} while (0)

#define FC_ITER(K_, VM_) do {                                                 \
    if ((K_) + 3 <= 15) FC_STAGE((K_) + 3);                                   \
    asm volatile("s_waitcnt vmcnt(" #VM_ ")" ::: "memory");                   \
    __builtin_amdgcn_s_barrier();                                             \
    __builtin_amdgcn_sched_barrier(0);                                        \
    const int b_ = (K_) & 3;                                                  \
    const char* Ab_ = (const char*)&Lds[b_][0][0];                            \
    const char* Bb_ = (const char*)&Lds[b_][1][0];                            \
    bf16x8 bfr_[4];                                                           \
    _Pragma("unroll")                                                         \
    for (int j_ = 0; j_ < 4; ++j_)                                            \
        bfr_[j_] = *reinterpret_cast<const bf16x8*>(                          \
            Bb_ + (wc * 64 + j_ * 16 + fr) * 64 + rsw);                       \
    bf16x8 afr_[8];                                                           \
    _Pragma("unroll")                                                         \
    for (int i_ = 0; i_ < 8; ++i_)                                            \
        afr_[i_] = *reinterpret_cast<const bf16x8*>(                          \
            Ab_ + (wr * 128 + i_ * 16 + fr) * 64 + rsw);                      \
    asm volatile("s_waitcnt lgkmcnt(0)" ::: "memory");                        \
    __builtin_amdgcn_sched_barrier(0);                                        \
    __builtin_amdgcn_s_barrier();                                             \
    __builtin_amdgcn_s_setprio(1);                                            \
    _Pragma("unroll")                                                         \
    for (int i_ = 0; i_ < 8; ++i_)                                            \
        _Pragma("unroll")                                                     \
        for (int j_ = 0; j_ < 4; ++j_)                                        \
            acc[i_][j_] = __builtin_amdgcn_mfma_f32_16x16x32_bf16(            \
                afr_[i_], bfr_[j_], acc[i_][j_], 0, 0, 0);                    \
    __builtin_amdgcn_s_setprio(0);                                            \
} while (0)

    FC_STAGE(0);
    FC_STAGE(1);
    FC_STAGE(2);

#pragma unroll 1
    for (int k = 0; k <= 12; ++k) {
        FC_ITER(k, 12);
    }
    FC_ITER(13, 8);
    FC_ITER(14, 4);
    FC_ITER(15, 0);

#undef FC_STAGE
#undef FC_ITER

    const int r0 = (lane >> 4) * 4;
#pragma unroll
    for (int i = 0; i < 8; ++i) {
        int row = m0 + wr * 128 + i * 16 + r0;
        if (row >= Mrows) continue;
#pragma unroll
        for (int j = 0; j < 4; ++j) {
            int col = n0 + wc * 64 + j * 16 + fr;
            if (col < Vz) {
                float bb = bias[col];
#pragma unroll
                for (int rr = 0; rr < 4; ++rr)
                    C[(size_t)(row + rr) * Vz + col] = acc[i][j][rr] + bb;
            }
        }
    }
}

// ---------------------------------------------------------------------------
// One LSTM step, K-split over waves. Grid (64, 4) x 256 thr.
__global__ __launch_bounds__(256) void lstm_step3(
    const float* __restrict__ xg,
    const ushort* __restrict__ Whi,
    const ushort* __restrict__ Ah,  const ushort* __restrict__ Alo,
    ushort* __restrict__ Oh, ushort* __restrict__ Ol,
    float* __restrict__ cst, ushort* __restrict__ hsb, int t)
{
    __shared__ float Cl[2][32][33];

    const int tid  = threadIdx.x;
    const int w    = tid >> 6;            // 0..3
    const int kh   = w >> 1;              // K-half
    const int ch   = w & 1;               // col-half (16 cols)
    const int lane = tid & 63;
    const int fr   = lane & 15;
    const int hi4  = lane >> 4;
    const int n0   = blockIdx.x * 32;     // 32 gate cols
    const int j0   = blockIdx.x * 8;      // 8 h-indices
    const int m0w  = blockIdx.y * 32;     // m quarter

    // prefetch elementwise operands
    const int lm = tid >> 3;
    const int hq = tid & 7;
    const int em = m0w + lm;
    const int ej = j0 + hq;
    const float4 xv = *reinterpret_cast<const float4*>(
        xg + ((size_t)em * TM + t) * G4 + n0 + hq * 4);
    const float cold = cst[(size_t)em * Hz + ej];

    f32x4 acc[2] = {};
    const size_t kbase = (size_t)kh * 256;
    const ushort* Bp  = Whi + (size_t)(n0 + ch * 16 + fr) * Hz + kbase;
    const ushort* Ap0 = Ah  + (size_t)(m0w + fr) * Hz + kbase;
    const ushort* Ap1 = Ah  + (size_t)(m0w + 16 + fr) * Hz + kbase;
    const ushort* Lp0 = Alo + (size_t)(m0w + fr) * Hz + kbase;
    const ushort* Lp1 = Alo + (size_t)(m0w + 16 + fr) * Hz + kbase;

#pragma unroll
    for (int kc = 0; kc < 8; ++kc) {
        const size_t koff = (size_t)kc * 32 + hi4 * 8;
        bf16x8 bv  = *reinterpret_cast<const bf16x8*>(Bp  + koff);
        bf16x8 ah0 = *reinterpret_cast<const bf16x8*>(Ap0 + koff);
        bf16x8 ah1 = *reinterpret_cast<const bf16x8*>(Ap1 + koff);
        bf16x8 al0 = *reinterpret_cast<const bf16x8*>(Lp0 + koff);
        bf16x8 al1 = *reinterpret_cast<const bf16x8*>(Lp1 + koff);
        acc[0] = __builtin_amdgcn_mfma_f32_16x16x32_bf16(ah0, bv, acc[0], 0, 0, 0);
        acc[1] = __builtin_amdgcn_mfma_f32_16x16x32_bf16(ah1, bv, acc[1], 0, 0, 0);
        acc[0] = __builtin_amdgcn_mfma_f32_16x16x32_bf16(al0, bv, acc[0], 0, 0, 0);
        acc[1] = __builtin_amdgcn_mfma_f32_16x16x32_bf16(al1, bv, acc[1], 0, 0, 0);
    }

#pragma unroll
    for (int i = 0; i < 2; ++i)
#pragma unroll
        for (int r = 0; r < 4; ++r)
            Cl[kh][i * 16 + hi4 * 4 + r][ch * 16 + fr] = acc[i][r];
    __syncthreads();

    {
        const int bc = hq * 4;
        float gi = Cl[0][lm][bc + 0] + Cl[1][lm][bc + 0] + xv.x;
        float gf = Cl[0][lm][bc + 1] + Cl[1][lm][bc + 1] + xv.y;
        float gg = Cl[0][lm][bc + 2] + Cl[1][lm][bc + 2] + xv.z;
        float go = Cl[0][lm][bc + 3] + Cl[1][lm][bc + 3] + xv.w;

        float ig = 1.f / (1.f + expf(-gi));
        float fg = 1.f / (1.f + expf(-gf));
        float gt = tanhf(gg);
        float og = 1.f / (1.f + expf(-go));

        float cn = fg * cold + ig * gt;
        float hv = og * tanhf(cn);
        cst[(size_t)em * Hz + ej] = cn;

        ushort hh = f2b(hv);
        ushort hl = f2b(hv - b2f(hh));
        Oh[(size_t)em * Hz + ej] = hh;
        Ol[(size_t)em * Hz + ej] = hl;
        hsb[((size_t)em * TM + t) * Hz + ej] = hh;
    }
}

// ---------------------------------------------------------------------------
extern "C" void kernel_launch(void* const* d_in, const int* in_sizes, int n_in,
                              void* d_out, int out_size, void* d_ws, size_t ws_size,
                              hipStream_t stream) {
    const float* features = (const float*)d_in[0];
    const int*   captions = (const int*)d_in[1];
    const float* emb_W    = (const float*)d_in[2];
    const float* W_ih     = (const float*)d_in[3];
    const float* W_hh     = (const float*)d_in[4];
    const float* b_ih     = (const float*)d_in[5];
    const float* b_hh     = (const float*)d_in[6];
    const float* Wh       = (const float*)d_in[7];
    const float* bh       = (const float*)d_in[8];
    const float* Wc       = (const float*)d_in[9];
    const float* bc       = (const float*)d_in[10];
    const float* fc_W     = (const float*)d_in[11];
    const float* fc_b     = (const float*)d_in[12];
    float* out = (float*)d_out;

    // workspace carve-up
    float* w    = (float*)d_ws;
    float* mean = w;                            // 262144 f
    float* xg   = mean + Bz * Fz;               // 8,126,464 f (partial overlaid)
    float* partial = xg;                        // [8][128][1024] f, used pre-xg
    float* c0f  = xg + (size_t)Mrows * G4;      // 65536 f
    float* bP   = c0f + Bz * Hz;                // 2048 f
    ushort* embg = (ushort*)(bP + G4);          // 3968*512
    ushort* WihP = embg + (size_t)Mrows * Ez;   // 2048*512
    ushort* Whi  = WihP + (size_t)G4 * Ez;      // 2048*512
    ushort* fcWb = Whi + (size_t)G4 * Hz;       // 10240*512
    ushort* hsb  = fcWb + (size_t)NPAD * Hz;    // 4096*512 region (3968 used)
    ushort* haHi = hsb + (size_t)MPAD * Hz;     // 128*512 each below
    ushort* haLo = haHi + Bz * Hz;
    ushort* hbHi = haLo + Bz * Hz;
    ushort* hbLo = hbHi + Bz * Hz;

    meanpool<<<(Bz * Fz / 4) / 256, 256, 0, stream>>>(features, mean);
    prep_all<<<(PR2 + 255) / 256, 256, 0, stream>>>(
        emb_W, captions, W_ih, W_hh, b_ih, b_hh, fc_W,
        embg, WihP, Whi, bP, fcWb);

    // init h0/c0
    initk<<<dim3(16, 2, 8), 256, 0, stream>>>(mean, Wh, Wc, partial);
    init_reduce<<<(128 * 1024) / 256, 256, 0, stream>>>(
        partial, bh, bc, haHi, haLo, c0f);

    // x-side gates: depth-3 pipelined 128^2
    xg8<<<496, 256, 0, stream>>>(embg, WihP, bP, xg);

    // recurrence
    for (int t = 0; t < TM; ++t) {
        const ushort* ih = (t & 1) ? hbHi : haHi;
        const ushort* il = (t & 1) ? hbLo : haLo;
        ushort* oh = (t & 1) ? haHi : hbHi;
        ushort* ol = (t & 1) ? haLo : hbLo;
        lstm_step3<<<dim3(64, 4), 256, 0, stream>>>(
            xg, Whi, ih, il, oh, ol, c0f, hsb, t);
    }

    // output projection: depth-3 pipelined, swizzled fc
    fc8<<<640, 512, 0, stream>>>(hsb, fcWb, fc_b, out);
}